// Round 14
// baseline (264.663 us; speedup 1.0000x reference)
//
#include <hip/hip_runtime.h>
#include <hip/hip_bf16.h>
#include <stdint.h>

// ---------------------------------------------------------------------------
// EfficientDAGNN: y_k = relu(concat(prev) @ (W_k*M_k)^T + b_k), 4 layers.
// R14 = R13 (258us best) with a 4-STAGE DMA pipeline: stages [32r][32k]
// (8KB/stage/wave, 4 stages = 32KB/wave = 128KB/block unchanged), G and A
// both issued 3 stages ahead -> prefetch distance ~3 KSTEPs (~1600cy),
// covering queue-inflated HBM latency (~1.5-2k cy at 80% load) that R13's
// 1-iter distance missed. Per-iter counted drain vmcnt(48/32/16/0).
// Split-bf16 (hi+lo) 3-term MFMA, fp32 split-K partials, phaseB reduce.
// Activation plane: [64][16384] bf16 hi+lo, cols: [x | y1 | y2 | y3].
// ---------------------------------------------------------------------------

typedef __attribute__((ext_vector_type(8))) short  s8v;    // 8 bf16 (MFMA frag)
typedef __attribute__((ext_vector_type(4))) float  f4v;
typedef __attribute__((ext_vector_type(2))) float  f2v;
typedef __attribute__((ext_vector_type(4))) unsigned short us4v;
typedef __attribute__((ext_vector_type(2))) unsigned short us2v;

#define LDA 16384              // activation plane leading dim (bf16 elems)
#define MFMA16 __builtin_amdgcn_mfma_f32_16x16x32_bf16

typedef __attribute__((address_space(3))) void       lds_void;
typedef const __attribute__((address_space(1))) void g_void;

// fp32 -> bf16 RTNE (no NaNs in this problem)
__device__ __forceinline__ short f2bf(float f) {
  unsigned int u = __builtin_bit_cast(unsigned int, f);
  u += 0x7fffu + ((u >> 16) & 1u);
  return (short)(u >> 16);
}
__device__ __forceinline__ float bf2f(short s) {
  unsigned int u = ((unsigned int)(unsigned short)s) << 16;
  return __builtin_bit_cast(float, u);
}

// ---------------------------------------------------------------------------
// splitx: x (fp32 [64][4096]) -> xh/xl bf16 into cols [0,4096) of the plane
// ---------------------------------------------------------------------------
__global__ void dag_splitx(const float* __restrict__ x,
                           ushort* __restrict__ xh, ushort* __restrict__ xl) {
  int idx = blockIdx.x * blockDim.x + threadIdx.x;   // 65536 float4 units
  int m = idx >> 10;
  int n = (idx & 1023) << 2;
  f4v v = *(const f4v*)(x + (size_t)m * 4096 + n);
  us4v h, l;
#pragma unroll
  for (int j = 0; j < 4; ++j) {
    short hh = f2bf(v[j]);
    h[j] = (unsigned short)hh;
    l[j] = (unsigned short)f2bf(v[j] - bf2f(hh));
  }
  *(us4v*)(xh + (size_t)m * LDA + n) = h;
  *(us4v*)(xl + (size_t)m * LDA + n) = l;
}

// ---------------------------------------------------------------------------
// Phase A: partial[split][64][4096] = A[64][klen] @ (W*M)^T[klen][4096]
// Wave tile 64m x 32n. 4-stage pipeline, stage = [32 rows][32 k] of W and M
// (DMA'd via global_load_lds w/ pre-swizzled source), 1 KSTEP per stage.
// Per-wave-private LDS quadrant: no barriers.
// grid = (32, SPLITK), block = 256 (4 waves), dynamic LDS 128KB.
// ---------------------------------------------------------------------------
struct RA { s8v ah0, ah1, ah2, ah3, al0, al1, al2, al3; };

template <int NSTEPS>
__global__ __launch_bounds__(256, 1) void dag_gemm_phaseA(
    const ushort* __restrict__ Ah,   // already offset to layer's col start
    const ushort* __restrict__ Al,
    const float*  __restrict__ W,    // [4096][K] row-major
    const float*  __restrict__ Mm,   // [4096][K]
    float*        __restrict__ partial,  // [SPLITK][64][4096]
    int K) {
  extern __shared__ float smem[];    // 128KB: 4 waves x 4 stages x (W|M 4KB)
  const int tid  = threadIdx.x;
  const int wave = tid >> 6, lane = tid & 63;
  const int l15  = lane & 15, blk = lane >> 4;
  const int n0   = blockIdx.x * 128 + wave * 32;   // wave's output-col base
  const int kbeg = blockIdx.y * (NSTEPS * 32);

  float* base = smem + wave * 8192;  // 32KB per wave; stage i at +i*2048
  const int srow8 = lane >> 3;       // 0..7: row within 8-row DMA group
  const int c8    = lane & 7;        // 16B chunk index within 128B row
  const int gc    = c8 ^ srow8;      // pre-swizzled global chunk

  // A: lane reads row (mt*16+l15), 8 consecutive k (16B of bf16)
  const ushort* ap  = Ah + (size_t)l15 * LDA + kbeg + blk * 8;
  const ushort* alp = Al + (size_t)l15 * LDA + kbeg + blk * 8;

  f4v acc[4][2];
#pragma unroll
  for (int i = 0; i < 4; ++i) {
    acc[i][0] = (f4v){0.f, 0.f, 0.f, 0.f};
    acc[i][1] = (f4v){0.f, 0.f, 0.f, 0.f};
  }
  RA a0, a1, a2, a3;
  auto AREF = [&](int i) -> RA& { return i == 0 ? a0 : i == 1 ? a1
                                       : i == 2 ? a2 : a3; };

  // DMA stage t into stage buffer (W 1024 floats | M 1024 floats).
  // Source pre-swizzled (gc = c8 ^ srow8); linear LDS dest: LDS row r,
  // chunk c then holds global chunk c ^ (r&7).
  auto GLDS = [&](int t) {
    float* WB = base + (t & 3) * 2048;
    float* MB = WB + 1024;
    const size_t kofs = (size_t)kbeg + t * 32 + gc * 4;
#pragma unroll
    for (int j = 0; j < 4; ++j) {
      int row = j * 8 + srow8;
      const float* ws = W  + (size_t)(n0 + row) * K + kofs;
      const float* ms = Mm + (size_t)(n0 + row) * K + kofs;
      __builtin_amdgcn_global_load_lds((g_void*)ws, (lds_void*)(WB + j * 256),
                                       16, 0, 0);
      __builtin_amdgcn_global_load_lds((g_void*)ms, (lds_void*)(MB + j * 256),
                                       16, 0, 0);
    }
  };
  auto LOADA = [&](RA& r, int ko) {
    r.ah0 = *(const s8v*)(ap  + ko);
    r.ah1 = *(const s8v*)(ap  + (size_t)16 * LDA + ko);
    r.ah2 = *(const s8v*)(ap  + (size_t)32 * LDA + ko);
    r.ah3 = *(const s8v*)(ap  + (size_t)48 * LDA + ko);
    r.al0 = *(const s8v*)(alp + ko);
    r.al1 = *(const s8v*)(alp + (size_t)16 * LDA + ko);
    r.al2 = *(const s8v*)(alp + (size_t)32 * LDA + ko);
    r.al3 = *(const s8v*)(alp + (size_t)48 * LDA + ko);
  };

  // One 32-k MFMA step consuming stage t: swizzled LDS reads, repack, 24 MFMA.
  auto KSTEP = [&](int t, RA& ra) {
    float* WL = base + (t & 3) * 2048;
    float* ML = WL + 1024;
    const int x  = l15 & 7;
    const int c0 = (2 * blk) ^ x, c1 = (2 * blk + 1) ^ x;
    const float* wr0 = WL + l15 * 32;
    const float* wr1 = WL + (l15 + 16) * 32;
    const float* mr0 = ML + l15 * 32;
    const float* mr1 = ML + (l15 + 16) * 32;
    f4v w0a = *(const f4v*)(wr0 + c0 * 4), w0b = *(const f4v*)(wr0 + c1 * 4);
    f4v w1a = *(const f4v*)(wr1 + c0 * 4), w1b = *(const f4v*)(wr1 + c1 * 4);
    f4v m0a = *(const f4v*)(mr0 + c0 * 4), m0b = *(const f4v*)(mr0 + c1 * 4);
    f4v m1a = *(const f4v*)(mr1 + c0 * 4), m1b = *(const f4v*)(mr1 + c1 * 4);

    s8v wh0, wl0, wh1, wl1;
#pragma unroll
    for (int j = 0; j < 4; ++j) {
      { float ww = w0a[j] * m0a[j]; short h = f2bf(ww);
        wh0[j]     = h; wl0[j]     = f2bf(ww - bf2f(h)); }
      { float ww = w0b[j] * m0b[j]; short h = f2bf(ww);
        wh0[j + 4] = h; wl0[j + 4] = f2bf(ww - bf2f(h)); }
      { float ww = w1a[j] * m1a[j]; short h = f2bf(ww);
        wh1[j]     = h; wl1[j]     = f2bf(ww - bf2f(h)); }
      { float ww = w1b[j] * m1b[j]; short h = f2bf(ww);
        wh1[j + 4] = h; wl1[j + 4] = f2bf(ww - bf2f(h)); }
    }
    // 3-term split product: ah*wh + al*wh + ah*wl  (al*wl ~ 2^-18, dropped)
    acc[0][0] = MFMA16(ra.ah0, wh0, acc[0][0], 0, 0, 0);
    acc[0][0] = MFMA16(ra.al0, wh0, acc[0][0], 0, 0, 0);
    acc[0][0] = MFMA16(ra.ah0, wl0, acc[0][0], 0, 0, 0);
    acc[1][0] = MFMA16(ra.ah1, wh0, acc[1][0], 0, 0, 0);
    acc[1][0] = MFMA16(ra.al1, wh0, acc[1][0], 0, 0, 0);
    acc[1][0] = MFMA16(ra.ah1, wl0, acc[1][0], 0, 0, 0);
    acc[2][0] = MFMA16(ra.ah2, wh0, acc[2][0], 0, 0, 0);
    acc[2][0] = MFMA16(ra.al2, wh0, acc[2][0], 0, 0, 0);
    acc[2][0] = MFMA16(ra.ah2, wl0, acc[2][0], 0, 0, 0);
    acc[3][0] = MFMA16(ra.ah3, wh0, acc[3][0], 0, 0, 0);
    acc[3][0] = MFMA16(ra.al3, wh0, acc[3][0], 0, 0, 0);
    acc[3][0] = MFMA16(ra.ah3, wl0, acc[3][0], 0, 0, 0);
    acc[0][1] = MFMA16(ra.ah0, wh1, acc[0][1], 0, 0, 0);
    acc[0][1] = MFMA16(ra.al0, wh1, acc[0][1], 0, 0, 0);
    acc[0][1] = MFMA16(ra.ah0, wl1, acc[0][1], 0, 0, 0);
    acc[1][1] = MFMA16(ra.ah1, wh1, acc[1][1], 0, 0, 0);
    acc[1][1] = MFMA16(ra.al1, wh1, acc[1][1], 0, 0, 0);
    acc[1][1] = MFMA16(ra.ah1, wl1, acc[1][1], 0, 0, 0);
    acc[2][1] = MFMA16(ra.ah2, wh1, acc[2][1], 0, 0, 0);
    acc[2][1] = MFMA16(ra.al2, wh1, acc[2][1], 0, 0, 0);
    acc[2][1] = MFMA16(ra.ah2, wl1, acc[2][1], 0, 0, 0);
    acc[3][1] = MFMA16(ra.ah3, wh1, acc[3][1], 0, 0, 0);
    acc[3][1] = MFMA16(ra.al3, wh1, acc[3][1], 0, 0, 0);
    acc[3][1] = MFMA16(ra.ah3, wl1, acc[3][1], 0, 0, 0);
  };

  // prologue: stages 0..2 (G then A per stage, uniform FIFO order)
  GLDS(0); LOADA(a0, 0);
  GLDS(1); LOADA(a1, 32);
  GLDS(2); LOADA(a2, 64);

#pragma unroll
  for (int t = 0; t < NSTEPS; ++t) {
    if (t + 3 < NSTEPS) {
      GLDS(t + 3);
      LOADA(AREF((t + 3) & 3), (t + 3) * 32);
    }
    // drain stage t's 16 loads (G then A); leave newer stages in flight
    const int rem = NSTEPS - 1 - t;
    if (rem >= 3)      asm volatile("s_waitcnt vmcnt(48)" ::: "memory");
    else if (rem == 2) asm volatile("s_waitcnt vmcnt(32)" ::: "memory");
    else if (rem == 1) asm volatile("s_waitcnt vmcnt(16)" ::: "memory");
    else               asm volatile("s_waitcnt vmcnt(0)"  ::: "memory");
    __builtin_amdgcn_sched_barrier(0);
    KSTEP(t, AREF(t & 3));
  }

  // write fp32 partials: C row m = mt*16 + blk*4 + r, col n = n0 + nt*16 + l15
  float* pout = partial + (size_t)blockIdx.y * (64 * 4096);
#pragma unroll
  for (int mt = 0; mt < 4; ++mt)
#pragma unroll
    for (int nt = 0; nt < 2; ++nt) {
      int n = n0 + nt * 16 + l15;
#pragma unroll
      for (int rr = 0; rr < 4; ++rr) {
        int m = mt * 16 + blk * 4 + rr;
        pout[(size_t)m * 4096 + n] = acc[mt][nt][rr];
      }
    }
}

// ---------------------------------------------------------------------------
// Phase B: reduce split-K partials + bias + relu; re-split to bf16 hi/lo
// (next layer's input); layer 4 writes fp32 d_out instead.
// ---------------------------------------------------------------------------
__global__ void dag_phaseB(const float* __restrict__ partial, int splitk,
                           const float* __restrict__ bias,
                           ushort* __restrict__ yh, ushort* __restrict__ yl,
                           float* __restrict__ yf) {
  int idx = blockIdx.x * blockDim.x + threadIdx.x;   // 131072 f2v units
  int m = idx >> 11;
  int n = (idx & 2047) << 1;
  const float* p = partial + (size_t)m * 4096 + n;
  float s0 = 0.f, s1 = 0.f;
#pragma unroll 4
  for (int sp = 0; sp < splitk; ++sp) {
    f2v v = *(const f2v*)(p + (size_t)sp * (64 * 4096));
    s0 += v[0]; s1 += v[1];
  }
  const f2v bv = *(const f2v*)(bias + n);
  s0 = fmaxf(s0 + bv[0], 0.f);
  s1 = fmaxf(s1 + bv[1], 0.f);
  if (yf) {
    *(f2v*)(yf + (size_t)m * 4096 + n) = (f2v){s0, s1};
  } else {
    us2v h, l;
    short h0 = f2bf(s0); h[0] = (unsigned short)h0;
    l[0] = (unsigned short)f2bf(s0 - bf2f(h0));
    short h1 = f2bf(s1); h[1] = (unsigned short)h1;
    l[1] = (unsigned short)f2bf(s1 - bf2f(h1));
    *(us2v*)(yh + (size_t)m * LDA + n) = h;
    *(us2v*)(yl + (size_t)m * LDA + n) = l;
  }
}

// ---------------------------------------------------------------------------
extern "C" void kernel_launch(void* const* d_in, const int* in_sizes, int n_in,
                              void* d_out, int out_size, void* d_ws, size_t ws_size,
                              hipStream_t stream) {
  (void)in_sizes; (void)n_in; (void)out_size;
  const float* x = (const float*)d_in[0];
  struct L { const float *W, *b, *M; int K, incol, outcol; };
  L Ls[4] = {
      {(const float*)d_in[1],  (const float*)d_in[2],  (const float*)d_in[3],  4096, 0,    4096},
      {(const float*)d_in[4],  (const float*)d_in[5],  (const float*)d_in[6],  8192, 0,    8192},
      {(const float*)d_in[7],  (const float*)d_in[8],  (const float*)d_in[9],  8192, 4096, 12288},
      {(const float*)d_in[10], (const float*)d_in[11], (const float*)d_in[12], 8192, 8192, 16384},
  };
  float* out = (float*)d_out;

  // workspace: Ah(2MB) | Al(2MB) | partial(SPLITK MB)
  char* ws = (char*)d_ws;
  ushort* Ah = (ushort*)ws;
  ushort* Al = (ushort*)(ws + (size_t)64 * LDA * 2);
  float* partial = (float*)(ws + (size_t)2 * 64 * LDA * 2);
  int SPLITK = 8;    // grid (32,8) = 256 blocks = exactly 1 resident block/CU
  while (SPLITK > 4 &&
         ws_size < (size_t)4 * 1024 * 1024 + (size_t)SPLITK * 1024 * 1024)
    SPLITK >>= 1;

  const int smem = 131072;   // 128KB dynamic LDS (> 64KB default: opt in)
  hipFuncSetAttribute((const void*)dag_gemm_phaseA<16>,
                      hipFuncAttributeMaxDynamicSharedMemorySize, smem);
  hipFuncSetAttribute((const void*)dag_gemm_phaseA<32>,
                      hipFuncAttributeMaxDynamicSharedMemorySize, smem);
  hipFuncSetAttribute((const void*)dag_gemm_phaseA<64>,
                      hipFuncAttributeMaxDynamicSharedMemorySize, smem);

  dag_splitx<<<256, 256, 0, stream>>>(x, Ah, Al);

  for (int k = 0; k < 4; ++k) {
    dim3 grid(32, SPLITK);
    const ushort* Ahp = Ah + Ls[k].incol;
    const ushort* Alp = Al + Ls[k].incol;
    int nsteps = (Ls[k].K / SPLITK) / 32;
    switch (nsteps) {
      case 16:
        dag_gemm_phaseA<16><<<grid, 256, smem, stream>>>(
            Ahp, Alp, Ls[k].W, Ls[k].M, partial, Ls[k].K);
        break;
      case 32:
        dag_gemm_phaseA<32><<<grid, 256, smem, stream>>>(
            Ahp, Alp, Ls[k].W, Ls[k].M, partial, Ls[k].K);
        break;
      default:
        dag_gemm_phaseA<64><<<grid, 256, smem, stream>>>(
            Ahp, Alp, Ls[k].W, Ls[k].M, partial, Ls[k].K);
        break;
    }
    bool last = (k == 3);
    dag_phaseB<<<512, 256, 0, stream>>>(
        partial, SPLITK, Ls[k].b,
        last ? (ushort*)nullptr : Ah + Ls[k].outcol,
        last ? (ushort*)nullptr : Al + Ls[k].outcol,
        last ? out : (float*)nullptr);
  }
}